// Round 2
// baseline (162.302 us; speedup 1.0000x reference)
//
#include <hip/hip_runtime.h>

// ContrastiveLoss: B=8192, D=128, T=0.1, SINGLE_POS=False.
// Classes c = 2*tt + tp in {0..3}; pos class = c^1, neg class = c^2.
// Rows are counting-sorted by class so each wave only visits the 2 column
// segments that can contribute, with per-segment-uniform {0,1} weights.

#define NB 8192
#define ND 128
#define NIB 64          // 8192 / 128 rows per i-block
#define JS 32           // column slices per i-block (power of 2!)
#define TEMP_INV 10.0f
#define LOG2E 1.4426950408889634f
#define EXPK (TEMP_INV * LOG2E)
#define GPAD_ROWS 32    // zero rows after G so masked tail tiles read zeros

typedef __attribute__((ext_vector_type(8))) short short8;
typedef __attribute__((ext_vector_type(4))) float f32x4;

// ws layout (bytes) — total ~2.14 MB
#define OFF_G    0                              // (8192+32) rows * 128 bf16
#define OFF_CLS  ((NB + GPAD_ROWS) * ND * 2)    // sorted classes u8[8192]
#define OFF_CO   (OFF_CLS + NB)                 // original classes u8[8192]
#define OFF_RL   (OFF_CO + NB)                  // local rank in (h,class) u16[8192]
#define OFF_CNT  (OFF_RL + NB * 2)              // per-h class hist int[16]
#define OFF_DONE (OFF_CNT + 64)                 // arrival counter int[1]
#define OFF_EP   (OFF_CNT + 256)                // f32[8192] accumulators
#define OFF_EN   (OFF_EP + NB * 4)
#define OFF_LS   (OFF_EN + NB * 4)

__device__ __forceinline__ unsigned short f2bf(float x) {
    unsigned int u = __float_as_uint(x);
    unsigned int r = (u + 0x7FFFu + ((u >> 16) & 1u)) >> 16;  // RNE
    return (unsigned short)r;
}

__device__ __forceinline__ float fast_exp2(float x) {
#if __has_builtin(__builtin_amdgcn_exp2f)
    return __builtin_amdgcn_exp2f(x);
#else
    return exp2f(x);
#endif
}

// 4 blocks x 256: classes, per-(h,class) histogram + local ranks (LDS atomics,
// order within class irrelevant), zero the accumulators / pad / out / counter.
__global__ __launch_bounds__(256) void classify_kernel(
    const int* __restrict__ dix, const int* __restrict__ tt, const int* __restrict__ tp,
    unsigned char* __restrict__ clsO, unsigned short* __restrict__ rlocal,
    int* __restrict__ cntP, int* __restrict__ done, unsigned short* __restrict__ Gpad,
    float* __restrict__ EpA, float* __restrict__ EnA, float* __restrict__ LsA,
    float* __restrict__ out)
{
    __shared__ int lh[4];
    const int h = blockIdx.x, tid = threadIdx.x;
    if (tid < 4) lh[tid] = 0;
    __syncthreads();
    #pragma unroll
    for (int k = 0; k < 8; ++k) {
        const int row = h * 2048 + k * 256 + tid;
        const int ix  = dix[row];
        const int c   = ((tt[ix] & 1) << 1) | (tp[ix] & 1);
        clsO[row] = (unsigned char)c;
        rlocal[row] = (unsigned short)atomicAdd(&lh[c], 1);
    }
    #pragma unroll
    for (int k = 0; k < 8; ++k) {
        const int i = h * 2048 + k * 256 + tid;
        EpA[i] = 0.f; EnA[i] = 0.f; LsA[i] = 0.f;
    }
    if (h == 0) {
        #pragma unroll
        for (int k = 0; k < 8; ++k)                       // 2048 u32 = 8 KB pad
            ((unsigned int*)Gpad)[k * 256 + tid] = 0u;
        if (tid == 0) { *out = 0.f; *done = 0; }
    }
    __syncthreads();
    if (tid < 4) cntP[h * 4 + tid] = lh[tid];
}

// 2048 blocks x 256 (wave per row): normalize row, scatter to sorted slot.
__global__ __launch_bounds__(256) void normscatter_kernel(
    const float* __restrict__ F, const unsigned char* __restrict__ clsO,
    const unsigned short* __restrict__ rlocal, const int* __restrict__ cntP,
    unsigned short* __restrict__ G, unsigned char* __restrict__ clsS)
{
    const int row  = blockIdx.x * 4 + (threadIdx.x >> 6);
    const int lane = threadIdx.x & 63;
    const int c = clsO[row];
    const int h = row >> 11;
    int base = (int)rlocal[row];
    #pragma unroll
    for (int cc = 0; cc < 3; ++cc)   // classes below c (wave-uniform branch)
        if (cc < c) base += cntP[cc] + cntP[4 + cc] + cntP[8 + cc] + cntP[12 + cc];
    #pragma unroll
    for (int hh = 0; hh < 3; ++hh)   // earlier hist blocks of same class
        if (hh < h) base += cntP[hh * 4 + c];

    const float2 v = *(const float2*)(F + row * ND + lane * 2);
    float ss = v.x * v.x + v.y * v.y;
    #pragma unroll
    for (int m = 1; m < 64; m <<= 1) ss += __shfl_xor(ss, m, 64);
    const float inv = rsqrtf(fmaxf(ss, 1e-24f));
    ushort2 st; st.x = f2bf(v.x * inv); st.y = f2bf(v.y * inv);
    *(ushort2*)(G + base * ND + lane * 2) = st;
    if (lane == 0) clsS[base] = (unsigned char)c;
}

// One column segment (uniform class). DOP: segment is pos for some row;
// DON: neg for some row. Weights wp/wn in {0,1} per row, hoisted from k-loop.
template<bool DOP, bool DON>
__device__ __forceinline__ void seg_tiles(
    const unsigned short* __restrict__ G,
    const short8 (&A)[2][4], unsigned int rcLo, unsigned int rcHi, int s,
    float (&Ep)[8], float (&En)[8], float (&Ls)[8],
    int cs, int ce, int t0, int t1, int l16, int q)
{
    const int s1 = s ^ 1, s2 = s ^ 2;
    float wp[8], wn[8];
    #pragma unroll
    for (int r = 0; r < 4; ++r) {
        const int cLo = (rcLo >> (8 * r)) & 0xff;
        const int cHi = (rcHi >> (8 * r)) & 0xff;
        if (DOP) { wp[r] = (cLo == s1) ? 1.f : 0.f; wp[4 + r] = (cHi == s1) ? 1.f : 0.f; }
        if (DON) { wn[r] = (cLo == s2) ? 1.f : 0.f; wn[4 + r] = (cHi == s2) ? 1.f : 0.f; }
    }
    for (int t = t0; t < t1; ++t) {
        const int j0 = cs + (t << 4);
        const unsigned short* gj = G + (j0 + l16) * ND + q * 8;
        short8 Bf[4];
        #pragma unroll
        for (int c = 0; c < 4; ++c) Bf[c] = *(const short8*)(gj + c * 32);
        f32x4 acc0 = {0.f, 0.f, 0.f, 0.f}, acc1 = {0.f, 0.f, 0.f, 0.f};
        #pragma unroll
        for (int c = 0; c < 4; ++c)
            acc0 = __builtin_amdgcn_mfma_f32_16x16x32_bf16(A[0][c], Bf[c], acc0, 0, 0, 0);
        #pragma unroll
        for (int c = 0; c < 4; ++c)
            acc1 = __builtin_amdgcn_mfma_f32_16x16x32_bf16(A[1][c], Bf[c], acc1, 0, 0, 0);
        if (j0 + 16 <= ce) {            // full tile (wave-uniform branch)
            #pragma unroll
            for (int r = 0; r < 4; ++r) {
                const float sv0 = acc0[r], sv1 = acc1[r];
                const float e0 = fast_exp2(sv0 * EXPK);
                const float e1 = fast_exp2(sv1 * EXPK);
                if (DOP) {
                    Ep[r]     = fmaf(wp[r],     e0,  Ep[r]);
                    Ls[r]     = fmaf(wp[r],     sv0, Ls[r]);
                    Ep[4 + r] = fmaf(wp[4 + r], e1,  Ep[4 + r]);
                    Ls[4 + r] = fmaf(wp[4 + r], sv1, Ls[4 + r]);
                }
                if (DON) {
                    En[r]     = fmaf(wn[r],     e0, En[r]);
                    En[4 + r] = fmaf(wn[4 + r], e1, En[4 + r]);
                }
            }
        } else {                        // tail tile: mask lanes past segment end
            const float vm = ((j0 + l16) < ce) ? 1.f : 0.f;
            #pragma unroll
            for (int r = 0; r < 4; ++r) {
                const float sv0 = acc0[r] * vm, sv1 = acc1[r] * vm;  // pad rows are 0 -> no NaN
                const float e0 = fast_exp2(sv0 * EXPK) * vm;
                const float e1 = fast_exp2(sv1 * EXPK) * vm;
                if (DOP) {
                    Ep[r]     = fmaf(wp[r],     e0,  Ep[r]);
                    Ls[r]     = fmaf(wp[r],     sv0, Ls[r]);
                    Ep[4 + r] = fmaf(wp[4 + r], e1,  Ep[4 + r]);
                    Ls[4 + r] = fmaf(wp[4 + r], sv1, Ls[4 + r]);
                }
                if (DON) {
                    En[r]     = fmaf(wn[r],     e0, En[r]);
                    En[4 + r] = fmaf(wn[4 + r], e1, En[4 + r]);
                }
            }
        }
    }
}

// Grid 64 i-blocks x 32 j-slices = 2048 blocks. Wave owns 32 sorted rows,
// visits only relevant class segments. Last block computes the loss.
__global__ __launch_bounds__(256, 4) void sim_kernel(
    const unsigned short* __restrict__ G, const unsigned char* __restrict__ clsS,
    const int* __restrict__ cntP, int* __restrict__ done,
    float* __restrict__ EpA, float* __restrict__ EnA, float* __restrict__ LsA,
    float* __restrict__ out)
{
    const int ib = blockIdx.x & (NIB - 1);
    const int jb = blockIdx.x >> 6;          // 0..JS-1
    const int wave = threadIdx.x >> 6, lane = threadIdx.x & 63;
    const int q = lane >> 4, l16 = lane & 15;
    const int ri = ib * 128 + wave * 32;

    // A fragments: rows ri+16t+l16, k-chunk c*32+q*8 (layout carried from verified kernel)
    short8 A[2][4];
    #pragma unroll
    for (int t = 0; t < 2; ++t)
        #pragma unroll
        for (int c = 0; c < 4; ++c)
            A[t][c] = *(const short8*)(G + (ri + 16 * t + l16) * ND + c * 32 + q * 8);

    // this lane's 8 output-row classes, packed (C/D row = 16t + 4q + r)
    const unsigned int rcLo = *(const unsigned int*)(clsS + ri + 4 * q);
    const unsigned int rcHi = *(const unsigned int*)(clsS + ri + 16 + 4 * q);
    const int wF = clsS[ri], wL = clsS[ri + 31];   // wave's (sorted) class range

    float Ep[8], En[8], Ls[8];
    #pragma unroll
    for (int i = 0; i < 8; ++i) { Ep[i] = 0.f; En[i] = 0.f; Ls[i] = 0.f; }

    int cs = 0;
    #pragma unroll 1
    for (int s = 0; s < 4; ++s) {
        const int len = cntP[s] + cntP[4 + s] + cntP[8 + s] + cntP[12 + s];
        const int ce = cs + len;
        const int s1 = s ^ 1, s2 = s ^ 2;
        const bool aP = (s1 >= wF) && (s1 <= wL);   // segment s is pos for some row
        const bool aN = (s2 >= wF) && (s2 <= wL);   // segment s is neg for some row
        if (aP || aN) {
            const int nt = (len + 15) >> 4;
            const int t0 = (jb * nt) >> 5;          // / JS
            const int t1 = ((jb + 1) * nt) >> 5;
            if (aP && aN) seg_tiles<true,  true >(G, A, rcLo, rcHi, s, Ep, En, Ls, cs, ce, t0, t1, l16, q);
            else if (aP)  seg_tiles<true,  false>(G, A, rcLo, rcHi, s, Ep, En, Ls, cs, ce, t0, t1, l16, q);
            else          seg_tiles<false, true >(G, A, rcLo, rcHi, s, Ep, En, Ls, cs, ce, t0, t1, l16, q);
        }
        cs = ce;
    }

    // reduce across the 16 column-lanes
    #pragma unroll
    for (int m = 1; m < 16; m <<= 1)
        #pragma unroll
        for (int i = 0; i < 8; ++i) {
            Ep[i] += __shfl_xor(Ep[i], m, 64);
            En[i] += __shfl_xor(En[i], m, 64);
            Ls[i] += __shfl_xor(Ls[i], m, 64);
        }
    if (l16 == 0) {
        #pragma unroll
        for (int t = 0; t < 2; ++t)
            #pragma unroll
            for (int r = 0; r < 4; ++r) {
                const int row = ri + 16 * t + 4 * q + r;
                const int i = t * 4 + r;
                atomicAdd(&EpA[row], Ep[i]);
                atomicAdd(&EnA[row], En[i]);
                atomicAdd(&LsA[row], Ls[i]);
            }
    }

    // ---- last arriving block finalizes the loss (no spin, no deadlock) ----
    __shared__ int lastFlag;
    __syncthreads();
    if (threadIdx.x == 0) {
        __threadfence();
        const int prev = atomicAdd(done, 1);   // device scope by default
        lastFlag = (prev == (int)gridDim.x - 1) ? 1 : 0;
    }
    __syncthreads();
    if (!lastFlag) return;

    const int tid = threadIdx.x;
    const int tot0 = cntP[0] + cntP[4] + cntP[8]  + cntP[12];
    const int tot1 = cntP[1] + cntP[5] + cntP[9]  + cntP[13];
    const int tot2 = cntP[2] + cntP[6] + cntP[10] + cntP[14];
    const int tot3 = cntP[3] + cntP[7] + cntP[11] + cntP[15];
    float csum = 0.f;
    #pragma unroll 4
    for (int k = 0; k < 32; ++k) {
        const int i = k * 256 + tid;
        const float ep = __hip_atomic_load(&EpA[i], __ATOMIC_RELAXED, __HIP_MEMORY_SCOPE_AGENT);
        const float en = __hip_atomic_load(&EnA[i], __ATOMIC_RELAXED, __HIP_MEMORY_SCOPE_AGENT);
        const float ls = __hip_atomic_load(&LsA[i], __ATOMIC_RELAXED, __HIP_MEMORY_SCOPE_AGENT);
        const int c = clsS[i];
        const int pc = c ^ 1, nc = c ^ 2;
        const int pcnt = (pc == 0) ? tot0 : (pc == 1) ? tot1 : (pc == 2) ? tot2 : tot3;
        const int ncnt = (nc == 0) ? tot0 : (nc == 1) ? tot1 : (nc == 2) ? tot2 : tot3;
        if (pcnt > 0 && ncnt > 0) {
            const float ld = logf(ep + en);
            csum += (TEMP_INV * ls - (float)pcnt * ld) / (float)pcnt;
        }
    }
    #pragma unroll
    for (int m = 1; m < 64; m <<= 1) csum += __shfl_xor(csum, m, 64);
    __shared__ float wsum[4];
    if ((tid & 63) == 0) wsum[tid >> 6] = csum;
    __syncthreads();
    if (tid == 0)
        *out = -(wsum[0] + wsum[1] + wsum[2] + wsum[3]) / (float)NB;
}

extern "C" void kernel_launch(void* const* d_in, const int* in_sizes, int n_in,
                              void* d_out, int out_size, void* d_ws, size_t ws_size,
                              hipStream_t stream) {
    const float* F = (const float*)d_in[0];
    const int* dix = (const int*)d_in[1];
    const int* tt  = (const int*)d_in[2];
    const int* tp  = (const int*)d_in[3];
    float* out = (float*)d_out;

    char* ws = (char*)d_ws;
    unsigned short* G   = (unsigned short*)(ws + OFF_G);
    unsigned char* clsS = (unsigned char*)(ws + OFF_CLS);
    unsigned char* clsO = (unsigned char*)(ws + OFF_CO);
    unsigned short* rl  = (unsigned short*)(ws + OFF_RL);
    int* cntP           = (int*)(ws + OFF_CNT);
    int* done           = (int*)(ws + OFF_DONE);
    float* EpA          = (float*)(ws + OFF_EP);
    float* EnA          = (float*)(ws + OFF_EN);
    float* LsA          = (float*)(ws + OFF_LS);
    unsigned short* Gpad = G + NB * ND;

    classify_kernel<<<4, 256, 0, stream>>>(dix, tt, tp, clsO, rl, cntP, done, Gpad,
                                           EpA, EnA, LsA, out);
    normscatter_kernel<<<2048, 256, 0, stream>>>(F, clsO, rl, cntP, G, clsS);
    sim_kernel<<<NIB * JS, 256, 0, stream>>>(G, clsS, cntP, done, EpA, EnA, LsA, out);
}

// Round 3
// 119.714 us; speedup vs baseline: 1.3557x; 1.3557x over previous
//
#include <hip/hip_runtime.h>

// ContrastiveLoss: B=8192, D=128, T=0.1, SINGLE_POS=False.
// Classes c = 2*tt + tp in {0..3}; pos class = c^1, neg class = c^2.
// Rows counting-sorted by class so each wave visits only the <=2 column
// segments that can contribute (half the MFMAs/exp2s of the dense kernel).
// Accumulation: per-(row, j-slice) partial stores (unique writer, NO global
// atomics — same-address atomics measured ~12 ns each in prior rounds).

#define NB 8192
#define ND 128
#define NIB 64          // i-blocks (128 rows each)
#define JS 16           // j-slices -> grid 64*16 = 1024 = 4 blocks/CU
#define TEMP_INV 10.0f
#define LOG2E 1.4426950408889634f
#define EXPK (TEMP_INV * LOG2E)

typedef __attribute__((ext_vector_type(8))) short short8;
typedef __attribute__((ext_vector_type(4))) float f32x4;

// ws layout (bytes) — total 3,678,272 (== footprint of the verified 138-us kernel)
#define OFF_G    0                         // 8192*128 bf16 = 2 MB (no pad; tail rows clamped)
#define OFF_CLS  (NB * ND * 2)             // sorted classes u8[8192]
#define OFF_CNT  (OFF_CLS + NB)            // per-h class hist int[16]
#define OFF_EPP  (OFF_CNT + 64)            // JS*8192 f32 partials
#define OFF_ENP  (OFF_EPP + NB * 4 * JS)
#define OFF_LSP  (OFF_ENP + NB * 4 * JS)
// aliased into the Ep partial region (dead before sim overwrites every slot):
#define OFF_CO   OFF_EPP                   // original classes u8[8192]
#define OFF_RL   (OFF_EPP + NB)            // local rank in (h,class) u16[8192]

__device__ __forceinline__ unsigned short f2bf(float x) {
    unsigned int u = __float_as_uint(x);
    unsigned int r = (u + 0x7FFFu + ((u >> 16) & 1u)) >> 16;  // RNE
    return (unsigned short)r;
}

__device__ __forceinline__ float fast_exp2(float x) {
#if __has_builtin(__builtin_amdgcn_exp2f)
    return __builtin_amdgcn_exp2f(x);
#else
    return exp2f(x);
#endif
}

// 4 blocks x 256: classes, per-(h,class) histogram + local ranks (LDS atomics),
// zero the output scalar.
__global__ __launch_bounds__(256) void classify_kernel(
    const int* __restrict__ dix, const int* __restrict__ tt, const int* __restrict__ tp,
    unsigned char* __restrict__ clsO, unsigned short* __restrict__ rlocal,
    int* __restrict__ cntP, float* __restrict__ out)
{
    __shared__ int lh[4];
    const int h = blockIdx.x, tid = threadIdx.x;
    if (tid < 4) lh[tid] = 0;
    __syncthreads();
    #pragma unroll
    for (int k = 0; k < 8; ++k) {
        const int row = h * 2048 + k * 256 + tid;
        const int ix  = dix[row];
        const int c   = ((tt[ix] & 1) << 1) | (tp[ix] & 1);
        clsO[row] = (unsigned char)c;
        rlocal[row] = (unsigned short)atomicAdd(&lh[c], 1);
    }
    if (h == 0 && tid == 0) *out = 0.0f;
    __syncthreads();
    if (tid < 4) cntP[h * 4 + tid] = lh[tid];
}

// 2048 blocks x 256 (wave per row): normalize row, scatter to sorted slot.
__global__ __launch_bounds__(256) void normscatter_kernel(
    const float* __restrict__ F, const unsigned char* __restrict__ clsO,
    const unsigned short* __restrict__ rlocal, const int* __restrict__ cntP,
    unsigned short* __restrict__ G, unsigned char* __restrict__ clsS)
{
    const int row  = blockIdx.x * 4 + (threadIdx.x >> 6);
    const int lane = threadIdx.x & 63;
    const int c = clsO[row];
    const int h = row >> 11;
    int base = (int)rlocal[row];
    #pragma unroll
    for (int cc = 0; cc < 3; ++cc)   // classes below c (wave-uniform branch)
        if (cc < c) base += cntP[cc] + cntP[4 + cc] + cntP[8 + cc] + cntP[12 + cc];
    #pragma unroll
    for (int hh = 0; hh < 3; ++hh)   // earlier hist blocks of same class
        if (hh < h) base += cntP[hh * 4 + c];

    const float2 v = *(const float2*)(F + row * ND + lane * 2);
    float ss = v.x * v.x + v.y * v.y;
    #pragma unroll
    for (int m = 1; m < 64; m <<= 1) ss += __shfl_xor(ss, m, 64);
    const float inv = rsqrtf(fmaxf(ss, 1e-24f));
    ushort2 st; st.x = f2bf(v.x * inv); st.y = f2bf(v.y * inv);
    *(ushort2*)(G + base * ND + lane * 2) = st;
    if (lane == 0) clsS[base] = (unsigned char)c;
}

// One column segment (uniform class). DOP: segment is pos for some row of this
// wave; DON: neg. Per-row {0,1} weights hoisted out of the tile loop.
template<bool DOP, bool DON>
__device__ __forceinline__ void seg_tiles(
    const unsigned short* __restrict__ G,
    const short8 (&A)[2][4], unsigned int rcLo, unsigned int rcHi, int s,
    float (&Ep)[8], float (&En)[8], float (&Ls)[8],
    int cs, int ce, int t0, int t1, int l16, int q)
{
    const int s1 = s ^ 1, s2 = s ^ 2;
    float wp[8], wn[8];
    #pragma unroll
    for (int r = 0; r < 4; ++r) {
        const int cLo = (rcLo >> (8 * r)) & 0xff;
        const int cHi = (rcHi >> (8 * r)) & 0xff;
        if (DOP) { wp[r] = (cLo == s1) ? 1.f : 0.f; wp[4 + r] = (cHi == s1) ? 1.f : 0.f; }
        if (DON) { wn[r] = (cLo == s2) ? 1.f : 0.f; wn[4 + r] = (cHi == s2) ? 1.f : 0.f; }
    }
    for (int t = t0; t < t1; ++t) {
        const int j0 = cs + (t << 4);
        int jc = j0 + l16;                    // clamp tail rows (masked anyway)
        jc = (jc < NB - 1) ? jc : (NB - 1);
        const unsigned short* gj = G + jc * ND + q * 8;
        short8 Bf[4];
        #pragma unroll
        for (int c = 0; c < 4; ++c) Bf[c] = *(const short8*)(gj + c * 32);
        f32x4 acc0 = {0.f, 0.f, 0.f, 0.f}, acc1 = {0.f, 0.f, 0.f, 0.f};
        #pragma unroll
        for (int c = 0; c < 4; ++c)
            acc0 = __builtin_amdgcn_mfma_f32_16x16x32_bf16(A[0][c], Bf[c], acc0, 0, 0, 0);
        #pragma unroll
        for (int c = 0; c < 4; ++c)
            acc1 = __builtin_amdgcn_mfma_f32_16x16x32_bf16(A[1][c], Bf[c], acc1, 0, 0, 0);
        if (j0 + 16 <= ce) {            // full tile (wave-uniform branch)
            #pragma unroll
            for (int r = 0; r < 4; ++r) {
                const float sv0 = acc0[r], sv1 = acc1[r];
                const float e0 = fast_exp2(sv0 * EXPK);
                const float e1 = fast_exp2(sv1 * EXPK);
                if (DOP) {
                    Ep[r]     = fmaf(wp[r],     e0,  Ep[r]);
                    Ls[r]     = fmaf(wp[r],     sv0, Ls[r]);
                    Ep[4 + r] = fmaf(wp[4 + r], e1,  Ep[4 + r]);
                    Ls[4 + r] = fmaf(wp[4 + r], sv1, Ls[4 + r]);
                }
                if (DON) {
                    En[r]     = fmaf(wn[r],     e0, En[r]);
                    En[4 + r] = fmaf(wn[4 + r], e1, En[4 + r]);
                }
            }
        } else {                        // tail tile: mask lanes past segment end
            const float vm = ((j0 + l16) < ce) ? 1.f : 0.f;
            #pragma unroll
            for (int r = 0; r < 4; ++r) {
                const float sv0 = acc0[r] * vm, sv1 = acc1[r] * vm;
                const float e0 = fast_exp2(sv0 * EXPK) * vm;
                const float e1 = fast_exp2(sv1 * EXPK) * vm;
                if (DOP) {
                    Ep[r]     = fmaf(wp[r],     e0,  Ep[r]);
                    Ls[r]     = fmaf(wp[r],     sv0, Ls[r]);
                    Ep[4 + r] = fmaf(wp[4 + r], e1,  Ep[4 + r]);
                    Ls[4 + r] = fmaf(wp[4 + r], sv1, Ls[4 + r]);
                }
                if (DON) {
                    En[r]     = fmaf(wn[r],     e0, En[r]);
                    En[4 + r] = fmaf(wn[4 + r], e1, En[4 + r]);
                }
            }
        }
    }
}

// Grid 64 i-blocks x 16 j-slices = 1024 blocks (one full pass, 4 blocks/CU).
// Wave owns 32 sorted rows, visits only its pos/neg class segments.
// Epilogue: plain per-(row, jb) partial stores — unique writer.
__global__ __launch_bounds__(256, 4) void sim_kernel(
    const unsigned short* __restrict__ G, const unsigned char* __restrict__ clsS,
    const int* __restrict__ cntP,
    float* __restrict__ EpP, float* __restrict__ EnP, float* __restrict__ LsP)
{
    const int ib = blockIdx.x & (NIB - 1);
    const int jb = blockIdx.x >> 6;          // 0..JS-1
    const int wave = threadIdx.x >> 6, lane = threadIdx.x & 63;
    const int q = lane >> 4, l16 = lane & 15;
    const int ri = ib * 128 + wave * 32;

    short8 A[2][4];
    #pragma unroll
    for (int t = 0; t < 2; ++t)
        #pragma unroll
        for (int c = 0; c < 4; ++c)
            A[t][c] = *(const short8*)(G + (ri + 16 * t + l16) * ND + c * 32 + q * 8);

    // this lane's 8 output-row classes (C/D row = 16t + 4q + r)
    const unsigned int rcLo = *(const unsigned int*)(clsS + ri + 4 * q);
    const unsigned int rcHi = *(const unsigned int*)(clsS + ri + 16 + 4 * q);
    const int wF = clsS[ri], wL = clsS[ri + 31];   // wave's sorted class range

    float Ep[8], En[8], Ls[8];
    #pragma unroll
    for (int i = 0; i < 8; ++i) { Ep[i] = 0.f; En[i] = 0.f; Ls[i] = 0.f; }

    int cs = 0;
    #pragma unroll 1
    for (int s = 0; s < 4; ++s) {
        const int len = cntP[s] + cntP[4 + s] + cntP[8 + s] + cntP[12 + s];
        const int ce = cs + len;
        const int s1 = s ^ 1, s2 = s ^ 2;
        const bool aP = (s1 >= wF) && (s1 <= wL);   // pos for some row of wave
        const bool aN = (s2 >= wF) && (s2 <= wL);   // neg for some row of wave
        if (aP || aN) {
            const int nt = (len + 15) >> 4;
            const int t0 = (jb * nt) >> 4;          // / JS
            const int t1 = ((jb + 1) * nt) >> 4;
            if (aP && aN) seg_tiles<true,  true >(G, A, rcLo, rcHi, s, Ep, En, Ls, cs, ce, t0, t1, l16, q);
            else if (aP)  seg_tiles<true,  false>(G, A, rcLo, rcHi, s, Ep, En, Ls, cs, ce, t0, t1, l16, q);
            else          seg_tiles<false, true >(G, A, rcLo, rcHi, s, Ep, En, Ls, cs, ce, t0, t1, l16, q);
        }
        cs = ce;
    }

    // reduce across the 16 column-lanes
    #pragma unroll
    for (int m = 1; m < 16; m <<= 1)
        #pragma unroll
        for (int i = 0; i < 8; ++i) {
            Ep[i] += __shfl_xor(Ep[i], m, 64);
            En[i] += __shfl_xor(En[i], m, 64);
            Ls[i] += __shfl_xor(Ls[i], m, 64);
        }
    if (l16 == 0) {
        #pragma unroll
        for (int t = 0; t < 2; ++t)
            #pragma unroll
            for (int r = 0; r < 4; ++r) {
                const int row = ri + 16 * t + 4 * q + r;
                const int i = t * 4 + r;
                EpP[jb * NB + row] = Ep[i];   // plain stores, unique writer
                EnP[jb * NB + row] = En[i];
                LsP[jb * NB + row] = Ls[i];
            }
    }
}

__global__ __launch_bounds__(256) void finalize_kernel(
    const float* __restrict__ EpP, const float* __restrict__ EnP,
    const float* __restrict__ LsP, const unsigned char* __restrict__ clsS,
    const int* __restrict__ cntP, float* __restrict__ out)
{
    const int i = blockIdx.x * 256 + threadIdx.x;
    const int tot0 = cntP[0] + cntP[4] + cntP[8]  + cntP[12];
    const int tot1 = cntP[1] + cntP[5] + cntP[9]  + cntP[13];
    const int tot2 = cntP[2] + cntP[6] + cntP[10] + cntP[14];
    const int tot3 = cntP[3] + cntP[7] + cntP[11] + cntP[15];
    const int c = clsS[i];
    const int pc = c ^ 1, nc = c ^ 2;
    const int pcnt = (pc == 0) ? tot0 : (pc == 1) ? tot1 : (pc == 2) ? tot2 : tot3;
    const int ncnt = (nc == 0) ? tot0 : (nc == 1) ? tot1 : (nc == 2) ? tot2 : tot3;
    float ep = 0.f, en = 0.f, ls = 0.f;
    #pragma unroll
    for (int jb = 0; jb < JS; ++jb) {
        ep += EpP[jb * NB + i];
        en += EnP[jb * NB + i];
        ls += LsP[jb * NB + i];
    }
    float contrib = 0.0f;
    if (pcnt > 0 && ncnt > 0) {
        const float ld = logf(ep + en);
        contrib = -(TEMP_INV * ls - (float)pcnt * ld) / ((float)pcnt * (float)NB);
    }
    #pragma unroll
    for (int m = 1; m < 64; m <<= 1) contrib += __shfl_xor(contrib, m, 64);
    __shared__ float wsum[4];
    if ((threadIdx.x & 63) == 0) wsum[threadIdx.x >> 6] = contrib;
    __syncthreads();
    if (threadIdx.x == 0)
        atomicAdd(out, wsum[0] + wsum[1] + wsum[2] + wsum[3]);
}

extern "C" void kernel_launch(void* const* d_in, const int* in_sizes, int n_in,
                              void* d_out, int out_size, void* d_ws, size_t ws_size,
                              hipStream_t stream) {
    const float* F = (const float*)d_in[0];
    const int* dix = (const int*)d_in[1];
    const int* tt  = (const int*)d_in[2];
    const int* tp  = (const int*)d_in[3];
    float* out = (float*)d_out;

    char* ws = (char*)d_ws;
    unsigned short* G   = (unsigned short*)(ws + OFF_G);
    unsigned char* clsS = (unsigned char*)(ws + OFF_CLS);
    int* cntP           = (int*)(ws + OFF_CNT);
    float* EpP          = (float*)(ws + OFF_EPP);
    float* EnP          = (float*)(ws + OFF_ENP);
    float* LsP          = (float*)(ws + OFF_LSP);
    unsigned char* clsO = (unsigned char*)(ws + OFF_CO);   // aliases EpP (dead
    unsigned short* rl  = (unsigned short*)(ws + OFF_RL);  //  before sim writes)

    classify_kernel<<<4, 256, 0, stream>>>(dix, tt, tp, clsO, rl, cntP, out);
    normscatter_kernel<<<2048, 256, 0, stream>>>(F, clsO, rl, cntP, G, clsS);
    sim_kernel<<<NIB * JS, 256, 0, stream>>>(G, clsS, cntP, EpP, EnP, LsP);
    finalize_kernel<<<NB / 256, 256, 0, stream>>>(EpP, EnP, LsP, clsS, cntP, out);
}

// Round 4
// 116.536 us; speedup vs baseline: 1.3927x; 1.0273x over previous
//
#include <hip/hip_runtime.h>

// ContrastiveLoss: B=8192, D=128, T=0.1, SINGLE_POS=False.
// Classes c = 2*tt + tp in {0..3}; pos class = c^1, neg class = c^2.
// Rows counting-sorted by class so each wave visits only the <=2 column
// segments that can contribute. B-tiles staged through LDS once per block
// (4 waves share), double-buffered with raw s_barrier + counted waits so
// prefetch loads stay in flight across barriers (no __syncthreads drain).

#define NB 8192
#define ND 128
#define NIB 64          // i-blocks (128 rows each)
#define JS 16           // j-slices -> grid 64*16 = 1024 = 4 blocks/CU
#define TEMP_INV 10.0f
#define LOG2E 1.4426950408889634f
#define EXPK (TEMP_INV * LOG2E)

typedef __attribute__((ext_vector_type(8))) short short8;
typedef __attribute__((ext_vector_type(4))) float f32x4;
typedef __attribute__((ext_vector_type(4))) unsigned int u32x4;

// ws layout (bytes) — total ~3.6 MB (same footprint family as verified kernels)
#define OFF_G    0                         // 8192*128 bf16 = 2 MB
#define OFF_CLS  (NB * ND * 2)             // sorted classes u8[8192]
#define OFF_CNT  (OFF_CLS + NB)            // per-h class hist int[16]
#define OFF_EPP  (OFF_CNT + 64)            // JS*8192 f32 partials
#define OFF_ENP  (OFF_EPP + NB * 4 * JS)
#define OFF_LSP  (OFF_ENP + NB * 4 * JS)
// aliased into the Ep partial region (dead before sim overwrites every slot):
#define OFF_CO   OFF_EPP                   // original classes u8[8192]
#define OFF_RL   (OFF_EPP + NB)            // local rank in (h,class) u16[8192]

__device__ __forceinline__ unsigned short f2bf(float x) {
    unsigned int u = __float_as_uint(x);
    unsigned int r = (u + 0x7FFFu + ((u >> 16) & 1u)) >> 16;  // RNE
    return (unsigned short)r;
}

__device__ __forceinline__ float fast_exp2(float x) {
#if __has_builtin(__builtin_amdgcn_exp2f)
    return __builtin_amdgcn_exp2f(x);
#else
    return exp2f(x);
#endif
}

// 4 blocks x 256: classes, per-(h,class) histogram + local ranks (LDS atomics),
// zero the output scalar.
__global__ __launch_bounds__(256) void classify_kernel(
    const int* __restrict__ dix, const int* __restrict__ tt, const int* __restrict__ tp,
    unsigned char* __restrict__ clsO, unsigned short* __restrict__ rlocal,
    int* __restrict__ cntP, float* __restrict__ out)
{
    __shared__ int lh[4];
    const int h = blockIdx.x, tid = threadIdx.x;
    if (tid < 4) lh[tid] = 0;
    __syncthreads();
    #pragma unroll
    for (int k = 0; k < 8; ++k) {
        const int row = h * 2048 + k * 256 + tid;
        const int ix  = dix[row];
        const int c   = ((tt[ix] & 1) << 1) | (tp[ix] & 1);
        clsO[row] = (unsigned char)c;
        rlocal[row] = (unsigned short)atomicAdd(&lh[c], 1);
    }
    if (h == 0 && tid == 0) *out = 0.0f;
    __syncthreads();
    if (tid < 4) cntP[h * 4 + tid] = lh[tid];
}

// 2048 blocks x 256 (wave per row): normalize row, scatter to sorted slot.
__global__ __launch_bounds__(256) void normscatter_kernel(
    const float* __restrict__ F, const unsigned char* __restrict__ clsO,
    const unsigned short* __restrict__ rlocal, const int* __restrict__ cntP,
    unsigned short* __restrict__ G, unsigned char* __restrict__ clsS)
{
    const int row  = blockIdx.x * 4 + (threadIdx.x >> 6);
    const int lane = threadIdx.x & 63;
    const int c = clsO[row];
    const int h = row >> 11;
    int base = (int)rlocal[row];
    #pragma unroll
    for (int cc = 0; cc < 3; ++cc)   // classes below c (wave-uniform branch)
        if (cc < c) base += cntP[cc] + cntP[4 + cc] + cntP[8 + cc] + cntP[12 + cc];
    #pragma unroll
    for (int hh = 0; hh < 3; ++hh)   // earlier hist blocks of same class
        if (hh < h) base += cntP[hh * 4 + c];

    const float2 v = *(const float2*)(F + row * ND + lane * 2);
    float ss = v.x * v.x + v.y * v.y;
    #pragma unroll
    for (int m = 1; m < 64; m <<= 1) ss += __shfl_xor(ss, m, 64);
    const float inv = rsqrtf(fmaxf(ss, 1e-24f));
    ushort2 st; st.x = f2bf(v.x * inv); st.y = f2bf(v.y * inv);
    *(ushort2*)(G + base * ND + lane * 2) = st;
    if (lane == 0) clsS[base] = (unsigned char)c;
}

// Grid 64 i-blocks x 16 j-slices = 1024 blocks (4 blocks/CU).
// Block-uniform segment walk; B-tiles staged via LDS (double buffer).
__global__ __launch_bounds__(256, 4) void sim_kernel(
    const unsigned short* __restrict__ G, const unsigned char* __restrict__ clsS,
    const int* __restrict__ cntP,
    float* __restrict__ EpP, float* __restrict__ EnP, float* __restrict__ LsP)
{
    // 272-byte row stride: 16B-aligned for ds_read_b128, odd multiple of 16B
    // to spread the 256B-strided fragment reads across banks.
    __shared__ __align__(16) unsigned short Bt[2][16][136];

    const int ib = blockIdx.x & (NIB - 1);
    const int jb = blockIdx.x >> 6;          // 0..JS-1
    const int wave = threadIdx.x >> 6, lane = threadIdx.x & 63;
    const int q = lane >> 4, l16 = lane & 15;
    const int ri = ib * 128 + wave * 32;
    const int wr = wave << 2;                // this wave's 4 staging rows

    short8 A[2][4];
    #pragma unroll
    for (int t = 0; t < 2; ++t)
        #pragma unroll
        for (int c = 0; c < 4; ++c)
            A[t][c] = *(const short8*)(G + (ri + 16 * t + l16) * ND + c * 32 + q * 8);

    // this lane's 8 output-row classes (C/D row = 16t + 4q + r)
    const unsigned int rcLo = *(const unsigned int*)(clsS + ri + 4 * q);
    const unsigned int rcHi = *(const unsigned int*)(clsS + ri + 16 + 4 * q);
    const int wF = clsS[ri], wL = clsS[ri + 31];         // wave class range
    const int bF = clsS[ib * 128], bL = clsS[ib * 128 + 127]; // block class range

    float Ep[8], En[8], Ls[8];
    #pragma unroll
    for (int i = 0; i < 8; ++i) { Ep[i] = 0.f; En[i] = 0.f; Ls[i] = 0.f; }

    const u32x4* G4 = (const u32x4*)G;       // 16B chunks; row = 16 chunks

    int cs = 0;
    #pragma unroll 1
    for (int s = 0; s < 4; ++s) {
        const int len = cntP[s] + cntP[4 + s] + cntP[8 + s] + cntP[12 + s];
        const int ce = cs + len;
        const int s1 = s ^ 1, s2 = s ^ 2;
        const bool aP = (s1 >= bF) && (s1 <= bL);   // block-uniform activity
        const bool aN = (s2 >= bF) && (s2 <= bL);
        if (aP || aN) {
            const int nt = (len + 15) >> 4;
            const int t0 = (jb * nt) >> 4;          // / JS
            const int t1 = ((jb + 1) * nt) >> 4;
            if (t0 < t1) {
                // per-wave {0,1} weights (all-zero if this wave doesn't need s)
                float wp[8], wn[8];
                #pragma unroll
                for (int r = 0; r < 4; ++r) {
                    const int cLo = (rcLo >> (8 * r)) & 0xff;
                    const int cHi = (rcHi >> (8 * r)) & 0xff;
                    wp[r]     = (cLo == s1) ? 1.f : 0.f;
                    wp[4 + r] = (cHi == s1) ? 1.f : 0.f;
                    wn[r]     = (cLo == s2) ? 1.f : 0.f;
                    wn[4 + r] = (cHi == s2) ? 1.f : 0.f;
                }
                const bool aPw = (s1 >= wF) && (s1 <= wL);  // wave-level (branch
                const bool aNw = (s2 >= wF) && (s2 <= wL);  //  only, no barriers)

                u32x4 st;
                // ---- stage tile t0 into Bt[0] ----
                {
                    int rw = cs + (t0 << 4) + wr + (lane >> 4);
                    rw = (rw < NB - 1) ? rw : (NB - 1);
                    st = G4[rw * 16 + (lane & 15)];
                    *(u32x4*)&Bt[0][wr + (lane >> 4)][(lane & 15) * 8] = st;
                }
                // issue loads for tile t0+1 (stay in flight across barrier)
                if (t0 + 1 < t1) {
                    int rw = cs + ((t0 + 1) << 4) + wr + (lane >> 4);
                    rw = (rw < NB - 1) ? rw : (NB - 1);
                    st = G4[rw * 16 + (lane & 15)];
                }
                asm volatile("s_waitcnt lgkmcnt(0)" ::: "memory"); // ds_write done
                asm volatile("s_barrier" ::: "memory");            // Bt[0] ready

                #pragma unroll 1
                for (int t = t0; t < t1; ++t) {
                    const int buf = (t - t0) & 1;
                    const int j0 = cs + (t << 4);
                    if (aPw || aNw) {
                        short8 Bf[4];
                        #pragma unroll
                        for (int c = 0; c < 4; ++c)
                            Bf[c] = *(const short8*)&Bt[buf][l16][c * 32 + q * 8];
                        f32x4 acc0 = {0.f, 0.f, 0.f, 0.f}, acc1 = {0.f, 0.f, 0.f, 0.f};
                        #pragma unroll
                        for (int c = 0; c < 4; ++c)
                            acc0 = __builtin_amdgcn_mfma_f32_16x16x32_bf16(A[0][c], Bf[c], acc0, 0, 0, 0);
                        #pragma unroll
                        for (int c = 0; c < 4; ++c)
                            acc1 = __builtin_amdgcn_mfma_f32_16x16x32_bf16(A[1][c], Bf[c], acc1, 0, 0, 0);
                        if (j0 + 16 <= ce) {            // full tile
                            #pragma unroll
                            for (int r = 0; r < 4; ++r) {
                                const float sv0 = acc0[r], sv1 = acc1[r];
                                const float e0 = fast_exp2(sv0 * EXPK);
                                const float e1 = fast_exp2(sv1 * EXPK);
                                if (aPw) {
                                    Ep[r]     = fmaf(wp[r],     e0,  Ep[r]);
                                    Ls[r]     = fmaf(wp[r],     sv0, Ls[r]);
                                    Ep[4 + r] = fmaf(wp[4 + r], e1,  Ep[4 + r]);
                                    Ls[4 + r] = fmaf(wp[4 + r], sv1, Ls[4 + r]);
                                }
                                if (aNw) {
                                    En[r]     = fmaf(wn[r],     e0, En[r]);
                                    En[4 + r] = fmaf(wn[4 + r], e1, En[4 + r]);
                                }
                            }
                        } else {                        // tail: mask past segment end
                            const float vm = ((j0 + l16) < ce) ? 1.f : 0.f;
                            #pragma unroll
                            for (int r = 0; r < 4; ++r) {
                                const float sv0 = acc0[r] * vm, sv1 = acc1[r] * vm;
                                const float e0 = fast_exp2(sv0 * EXPK) * vm;
                                const float e1 = fast_exp2(sv1 * EXPK) * vm;
                                if (aPw) {
                                    Ep[r]     = fmaf(wp[r],     e0,  Ep[r]);
                                    Ls[r]     = fmaf(wp[r],     sv0, Ls[r]);
                                    Ep[4 + r] = fmaf(wp[4 + r], e1,  Ep[4 + r]);
                                    Ls[4 + r] = fmaf(wp[4 + r], sv1, Ls[4 + r]);
                                }
                                if (aNw) {
                                    En[r]     = fmaf(wn[r],     e0, En[r]);
                                    En[4 + r] = fmaf(wn[4 + r], e1, En[4 + r]);
                                }
                            }
                        }
                    }
                    asm volatile("s_barrier" ::: "memory");   // all done reading Bt[buf]
                    if (t + 1 < t1) {
                        // write tile t+1 (regs) into the other buffer
                        *(u32x4*)&Bt[buf ^ 1][wr + (lane >> 4)][(lane & 15) * 8] = st;
                        // issue loads for tile t+2 (hidden under next compute)
                        if (t + 2 < t1) {
                            int rw = cs + ((t + 2) << 4) + wr + (lane >> 4);
                            rw = (rw < NB - 1) ? rw : (NB - 1);
                            st = G4[rw * 16 + (lane & 15)];
                        }
                        asm volatile("s_waitcnt lgkmcnt(0)" ::: "memory"); // write done
                        asm volatile("s_barrier" ::: "memory");            // visible
                    }
                }
            }
        }
        cs = ce;
    }

    // reduce across the 16 column-lanes
    #pragma unroll
    for (int m = 1; m < 16; m <<= 1)
        #pragma unroll
        for (int i = 0; i < 8; ++i) {
            Ep[i] += __shfl_xor(Ep[i], m, 64);
            En[i] += __shfl_xor(En[i], m, 64);
            Ls[i] += __shfl_xor(Ls[i], m, 64);
        }
    if (l16 == 0) {
        #pragma unroll
        for (int t = 0; t < 2; ++t)
            #pragma unroll
            for (int r = 0; r < 4; ++r) {
                const int row = ri + 16 * t + 4 * q + r;
                const int i = t * 4 + r;
                EpP[jb * NB + row] = Ep[i];   // plain stores, unique writer
                EnP[jb * NB + row] = En[i];
                LsP[jb * NB + row] = Ls[i];
            }
    }
}

__global__ __launch_bounds__(256) void finalize_kernel(
    const float* __restrict__ EpP, const float* __restrict__ EnP,
    const float* __restrict__ LsP, const unsigned char* __restrict__ clsS,
    const int* __restrict__ cntP, float* __restrict__ out)
{
    const int i = blockIdx.x * 256 + threadIdx.x;
    const int tot0 = cntP[0] + cntP[4] + cntP[8]  + cntP[12];
    const int tot1 = cntP[1] + cntP[5] + cntP[9]  + cntP[13];
    const int tot2 = cntP[2] + cntP[6] + cntP[10] + cntP[14];
    const int tot3 = cntP[3] + cntP[7] + cntP[11] + cntP[15];
    const int c = clsS[i];
    const int pc = c ^ 1, nc = c ^ 2;
    const int pcnt = (pc == 0) ? tot0 : (pc == 1) ? tot1 : (pc == 2) ? tot2 : tot3;
    const int ncnt = (nc == 0) ? tot0 : (nc == 1) ? tot1 : (nc == 2) ? tot2 : tot3;
    float ep = 0.f, en = 0.f, ls = 0.f;
    #pragma unroll
    for (int jb = 0; jb < JS; ++jb) {
        ep += EpP[jb * NB + i];
        en += EnP[jb * NB + i];
        ls += LsP[jb * NB + i];
    }
    float contrib = 0.0f;
    if (pcnt > 0 && ncnt > 0) {
        const float ld = logf(ep + en);
        contrib = -(TEMP_INV * ls - (float)pcnt * ld) / ((float)pcnt * (float)NB);
    }
    #pragma unroll
    for (int m = 1; m < 64; m <<= 1) contrib += __shfl_xor(contrib, m, 64);
    __shared__ float wsum[4];
    if ((threadIdx.x & 63) == 0) wsum[threadIdx.x >> 6] = contrib;
    __syncthreads();
    if (threadIdx.x == 0)
        atomicAdd(out, wsum[0] + wsum[1] + wsum[2] + wsum[3]);
}

extern "C" void kernel_launch(void* const* d_in, const int* in_sizes, int n_in,
                              void* d_out, int out_size, void* d_ws, size_t ws_size,
                              hipStream_t stream) {
    const float* F = (const float*)d_in[0];
    const int* dix = (const int*)d_in[1];
    const int* tt  = (const int*)d_in[2];
    const int* tp  = (const int*)d_in[3];
    float* out = (float*)d_out;

    char* ws = (char*)d_ws;
    unsigned short* G   = (unsigned short*)(ws + OFF_G);
    unsigned char* clsS = (unsigned char*)(ws + OFF_CLS);
    int* cntP           = (int*)(ws + OFF_CNT);
    float* EpP          = (float*)(ws + OFF_EPP);
    float* EnP          = (float*)(ws + OFF_ENP);
    float* LsP          = (float*)(ws + OFF_LSP);
    unsigned char* clsO = (unsigned char*)(ws + OFF_CO);   // aliases EpP (dead
    unsigned short* rl  = (unsigned short*)(ws + OFF_RL);  //  before sim writes)

    classify_kernel<<<4, 256, 0, stream>>>(dix, tt, tp, clsO, rl, cntP, out);
    normscatter_kernel<<<2048, 256, 0, stream>>>(F, clsO, rl, cntP, G, clsS);
    sim_kernel<<<NIB * JS, 256, 0, stream>>>(G, clsS, cntP, EpP, EnP, LsP);
    finalize_kernel<<<NB / 256, 256, 0, stream>>>(EpP, EnP, LsP, clsS, cntP, out);
}